// Round 1
// baseline (1352.355 us; speedup 1.0000x reference)
//
#include <hip/hip_runtime.h>

#define N_ROWS 16384
#define DDIM   256
#define VCODES 8192
#define BETA   0.25f

#define BM 128   // rows per block tile
#define BV 128   // codes per v-tile
#define KC 32    // K chunk
#define KP (KC + 4)  // padded LDS stride (36 floats == 4-bank shift/row)
#define VSPLIT 2

// ---------------- codebook norms ----------------
__global__ void cbnorm_k(const float* __restrict__ cb, float* __restrict__ cbnorm) {
    int gtid = blockIdx.x * blockDim.x + threadIdx.x;
    int wave = gtid >> 6;          // one wave per code row
    int lane = threadIdx.x & 63;
    if (wave >= VCODES) return;
    float4 v = *(const float4*)(cb + (size_t)wave * DDIM + lane * 4);
    float s = v.x * v.x + v.y * v.y + v.z * v.z + v.w * v.w;
    #pragma unroll
    for (int m = 32; m; m >>= 1) s += __shfl_xor(s, m, 64);
    if (lane == 0) cbnorm[wave] = s;
}

// ---------------- main distance + argmin ----------------
// grid (N_ROWS/BM, VSPLIT), block 256
__global__ __launch_bounds__(256, 2)
void vq_main(const float* __restrict__ lat, const float* __restrict__ cb,
             const float* __restrict__ cbnorm,
             float* __restrict__ pmin, int* __restrict__ pidx) {
    __shared__ float As[BM][KP];
    __shared__ float Bs[BV][KP];

    const int tid = threadIdx.x;
    const int tx = tid & 15;       // code direction
    const int ty = tid >> 4;       // row direction
    const int r0 = blockIdx.x * BM;
    const int vbase = blockIdx.y * (VCODES / VSPLIT);

    float rmin[8];
    int   ridx[8];
    #pragma unroll
    for (int i = 0; i < 8; i++) { rmin[i] = 3.4e38f; ridx[i] = 0; }

    for (int vt = 0; vt < VCODES / VSPLIT; vt += BV) {
        float acc[8][8];
        #pragma unroll
        for (int i = 0; i < 8; i++)
            #pragma unroll
            for (int j = 0; j < 8; j++) acc[i][j] = 0.0f;

        for (int kc = 0; kc < DDIM; kc += KC) {
            // cooperative loads: BM*KC floats = 1024 float4 each; 4 per thread
            #pragma unroll
            for (int l = 0; l < 4; l++) {
                int q = l * 256 + tid;
                int row = q >> 3;          // 8 float4 per row (KC=32)
                int kq = q & 7;
                float4 v = *(const float4*)&lat[(size_t)(r0 + row) * DDIM + kc + kq * 4];
                *(float4*)&As[row][kq * 4] = v;
            }
            #pragma unroll
            for (int l = 0; l < 4; l++) {
                int q = l * 256 + tid;
                int row = q >> 3;
                int kq = q & 7;
                float4 v = *(const float4*)&cb[(size_t)(vbase + vt + row) * DDIM + kc + kq * 4];
                *(float4*)&Bs[row][kq * 4] = v;
            }
            __syncthreads();

            #pragma unroll 2
            for (int k = 0; k < KC; k += 4) {
                float4 a[8], b[8];
                #pragma unroll
                for (int i = 0; i < 8; i++) a[i] = *(float4*)&As[i * 16 + ty][k];
                #pragma unroll
                for (int j = 0; j < 8; j++) b[j] = *(float4*)&Bs[j * 16 + tx][k];
                #pragma unroll
                for (int i = 0; i < 8; i++)
                    #pragma unroll
                    for (int j = 0; j < 8; j++) {
                        acc[i][j] += a[i].x * b[j].x;
                        acc[i][j] += a[i].y * b[j].y;
                        acc[i][j] += a[i].z * b[j].z;
                        acc[i][j] += a[i].w * b[j].w;
                    }
            }
            __syncthreads();
        }

        // score = ||e||^2 - 2 x.e ; update running argmin
        #pragma unroll
        for (int j = 0; j < 8; j++) {
            int c = vbase + vt + j * 16 + tx;
            float cn = cbnorm[c];
            #pragma unroll
            for (int i = 0; i < 8; i++) {
                float s = cn - 2.0f * acc[i][j];
                if (s < rmin[i] || (s == rmin[i] && c < ridx[i])) {
                    rmin[i] = s;
                    ridx[i] = c;
                }
            }
        }
    }

    // reduce across the 16 tx lanes sharing each row (contiguous 16-lane groups)
    #pragma unroll
    for (int i = 0; i < 8; i++) {
        float m = rmin[i];
        int id = ridx[i];
        #pragma unroll
        for (int off = 8; off; off >>= 1) {
            float om = __shfl_xor(m, off, 64);
            int oid = __shfl_xor(id, off, 64);
            if (om < m || (om == m && oid < id)) { m = om; id = oid; }
        }
        if (tx == 0) {
            int row = r0 + i * 16 + ty;
            pmin[row * VSPLIT + blockIdx.y] = m;
            pidx[row * VSPLIT + blockIdx.y] = id;
        }
    }
}

// ---------------- combine + gather + partial loss ----------------
// block 256 = 4 rows x 64 lanes; grid N_ROWS/4
__global__ void quantize_k(const float* __restrict__ lat, const float* __restrict__ cb,
                           const float* __restrict__ pmin, const int* __restrict__ pidx,
                           float* __restrict__ out_q, float* __restrict__ out_idx,
                           float* __restrict__ loss_part) {
    int tid = threadIdx.x;
    int lane = tid & 63;
    int rsub = tid >> 6;
    int row = blockIdx.x * 4 + rsub;

    float m0 = pmin[row * VSPLIT + 0];
    float m1 = pmin[row * VSPLIT + 1];
    int i0 = pidx[row * VSPLIT + 0];
    int i1 = pidx[row * VSPLIT + 1];
    int idx = (m1 < m0 || (m1 == m0 && i1 < i0)) ? i1 : i0;

    float4 q = *(const float4*)&cb[(size_t)idx * DDIM + lane * 4];
    float4 x = *(const float4*)&lat[(size_t)row * DDIM + lane * 4];
    *(float4*)&out_q[(size_t)row * DDIM + lane * 4] = q;
    if (lane == 0) out_idx[row] = (float)idx;

    float dx = q.x - x.x, dy = q.y - x.y, dz = q.z - x.z, dw = q.w - x.w;
    float s = dx * dx + dy * dy + dz * dz + dw * dw;
    #pragma unroll
    for (int m = 32; m; m >>= 1) s += __shfl_xor(s, m, 64);

    __shared__ float red[4];
    if (lane == 0) red[rsub] = s;
    __syncthreads();
    if (tid == 0) loss_part[blockIdx.x] = red[0] + red[1] + red[2] + red[3];
}

// ---------------- deterministic loss reduction ----------------
__global__ void loss_k(const float* __restrict__ part, float* __restrict__ out_loss) {
    float s = 0.0f;
    for (int i = threadIdx.x; i < N_ROWS / 4; i += 256) s += part[i];
    #pragma unroll
    for (int m = 32; m; m >>= 1) s += __shfl_xor(s, m, 64);
    __shared__ float wsum[4];
    int lane = threadIdx.x & 63, w = threadIdx.x >> 6;
    if (lane == 0) wsum[w] = s;
    __syncthreads();
    if (threadIdx.x == 0) {
        float t = wsum[0] + wsum[1] + wsum[2] + wsum[3];
        *out_loss = (1.0f + BETA) * t / (float)((size_t)N_ROWS * DDIM);
    }
}

extern "C" void kernel_launch(void* const* d_in, const int* in_sizes, int n_in,
                              void* d_out, int out_size, void* d_ws, size_t ws_size,
                              hipStream_t stream) {
    const float* lat = (const float*)d_in[0];   // [16,32,32,256] fp32
    const float* cb  = (const float*)d_in[1];   // [8192,256] fp32

    float* ws = (float*)d_ws;
    float* cbnorm   = ws;                                   // 8192
    float* pmin     = ws + VCODES;                          // 16384*2
    int*   pidx     = (int*)(ws + VCODES + N_ROWS * VSPLIT);        // 16384*2
    float* losspart = ws + VCODES + 2 * N_ROWS * VSPLIT;            // 4096

    float* out_q    = (float*)d_out;                        // 4194304 floats
    float* out_loss = (float*)d_out + (size_t)N_ROWS * DDIM;        // 1
    float* out_idx  = out_loss + 1;                         // 16384 (as fp32)

    cbnorm_k<<<(VCODES * 64) / 256, 256, 0, stream>>>(cb, cbnorm);

    dim3 grid(N_ROWS / BM, VSPLIT);
    vq_main<<<grid, 256, 0, stream>>>(lat, cb, cbnorm, pmin, pidx);

    quantize_k<<<N_ROWS / 4, 256, 0, stream>>>(lat, cb, pmin, pidx,
                                               out_q, out_idx, losspart);
    loss_k<<<1, 256, 0, stream>>>(losspart, out_loss);
}

// Round 2
// 301.445 us; speedup vs baseline: 4.4862x; 4.4862x over previous
//
#include <hip/hip_runtime.h>

#define N_ROWS 16384
#define DDIM   256
#define VCODES 8192
#define BETA   0.25f

using f16   = _Float16;
using f16x4 = __attribute__((ext_vector_type(4))) _Float16;
using f16x8 = __attribute__((ext_vector_type(8))) _Float16;
using f32x4 = __attribute__((ext_vector_type(4))) float;

typedef __attribute__((address_space(1))) const unsigned int gu32_t;
typedef __attribute__((address_space(3))) unsigned int       lu32_t;

__device__ __forceinline__ void gload16(const void* g, void* l) {
    __builtin_amdgcn_global_load_lds((gu32_t*)g, (lu32_t*)l, 16, 0, 0);
}

// ---------- split latents: x = hi + lo (fp16 pair), layout [row][hi 0..255 | lo 256..511]
__global__ void split_lat(const float* __restrict__ lat, f16* __restrict__ Ah) {
    int t = blockIdx.x * 256 + threadIdx.x;       // 1048576 threads, 4 floats each
    float4 x = *(const float4*)&lat[(size_t)t * 4];
    int row = t >> 6;
    int col = (t & 63) * 4;
    f16 h0 = (f16)x.x, h1 = (f16)x.y, h2 = (f16)x.z, h3 = (f16)x.w;
    f16 l0 = (f16)(x.x - (float)h0), l1 = (f16)(x.y - (float)h1);
    f16 l2 = (f16)(x.z - (float)h2), l3 = (f16)(x.w - (float)h3);
    f16x4 hi = {h0, h1, h2, h3}, lo = {l0, l1, l2, l3};
    *(f16x4*)&Ah[(size_t)row * 512 + col]       = hi;
    *(f16x4*)&Ah[(size_t)row * 512 + 256 + col] = lo;
}

// ---------- split codebook: E = 64*e, layout [code][Ehi 0..255 | Elo 256..511]
__global__ void split_cb(const float* __restrict__ cb, f16* __restrict__ Bh) {
    int t = blockIdx.x * 256 + threadIdx.x;       // 524288 threads
    float4 e = *(const float4*)&cb[(size_t)t * 4];
    float ex = e.x * 64.0f, ey = e.y * 64.0f, ez = e.z * 64.0f, ew = e.w * 64.0f;
    int row = t >> 6;
    int col = (t & 63) * 4;
    f16 h0 = (f16)ex, h1 = (f16)ey, h2 = (f16)ez, h3 = (f16)ew;
    f16 l0 = (f16)(ex - (float)h0), l1 = (f16)(ey - (float)h1);
    f16 l2 = (f16)(ez - (float)h2), l3 = (f16)(ew - (float)h3);
    f16x4 hi = {h0, h1, h2, h3}, lo = {l0, l1, l2, l3};
    *(f16x4*)&Bh[(size_t)row * 512 + col]       = hi;
    *(f16x4*)&Bh[(size_t)row * 512 + 256 + col] = lo;
}

// ---------- codebook norms (fp32, exact path) ----------
__global__ void cbnorm_k(const float* __restrict__ cb, float* __restrict__ cbnorm) {
    int gtid = blockIdx.x * blockDim.x + threadIdx.x;
    int wave = gtid >> 6;
    int lane = threadIdx.x & 63;
    if (wave >= VCODES) return;
    float4 v = *(const float4*)(cb + (size_t)wave * DDIM + lane * 4);
    float s = v.x * v.x + v.y * v.y + v.z * v.z + v.w * v.w;
    #pragma unroll
    for (int m = 32; m; m >>= 1) s += __shfl_xor(s, m, 64);
    if (lane == 0) cbnorm[wave] = s;
}

// ---------- main: K=768 fp16-split GEMM + in-register argmin ----------
// grid (16384/128, 8192/512) = (128,16); block 256 (4 waves, 2x2 wave grid)
__global__ __launch_bounds__(256, 2)
void vq_mfma(const f16* __restrict__ Ah, const f16* __restrict__ Bh,
             const float* __restrict__ cbn,
             float* __restrict__ pmin, int* __restrict__ pidx) {
    __shared__ __align__(16) f16 As[128 * 32];
    __shared__ __align__(16) f16 Bs[128 * 32];

    const int tid  = threadIdx.x;
    const int lane = tid & 63;
    const int w    = tid >> 6;
    const int wr   = w >> 1, wc = w & 1;
    const int l15  = lane & 15;
    const int l4   = lane >> 4;
    const int r0   = blockIdx.x * 128;
    const int vgrp = blockIdx.y;

    float rmin[4][4];
    int   ridx[4][4];
    #pragma unroll
    for (int m = 0; m < 4; m++)
        #pragma unroll
        for (int r = 0; r < 4; r++) { rmin[m][r] = 3.4e38f; ridx[m][r] = 0x7fffffff; }

    for (int vt = 0; vt < 4; vt++) {
        const int v0 = vgrp * 512 + vt * 128;
        f32x4 acc[4][4];
        #pragma unroll
        for (int m = 0; m < 4; m++)
            #pragma unroll
            for (int n = 0; n < 4; n++) acc[m][n] = (f32x4){0.f, 0.f, 0.f, 0.f};

        for (int kc = 0; kc < 768; kc += 32) {
            // virtual-K -> stored column bases:
            // A' = [x_hi | x_lo], B' = [E_hi | E_lo]
            // products: k<256: hi*Ehi ; 256..511: hi*Elo ; 512..767: lo*Ehi
            const int acol = (kc < 256) ? kc : kc - 256;
            const int bcol = (kc < 512) ? kc : kc - 512;
            #pragma unroll
            for (int i = 0; i < 2; i++) {
                const int off  = i * 4096 + tid * 16;     // bytes within 8 KB tile
                const int row  = off >> 6;                // 64 B per row (32 f16)
                const int colh = (off >> 1) & 31;         // f16 index in row
                gload16(Ah + (((size_t)(r0 + row)) << 9) + acol + colh, (char*)As + off);
                gload16(Bh + (((size_t)(v0 + row)) << 9) + bcol + colh, (char*)Bs + off);
            }
            __syncthreads();

            f16x8 af[4], bf[4];
            #pragma unroll
            for (int m = 0; m < 4; m++)
                af[m] = *(const f16x8*)(As + (wr * 64 + m * 16 + l15) * 32 + l4 * 8);
            #pragma unroll
            for (int n = 0; n < 4; n++)
                bf[n] = *(const f16x8*)(Bs + (wc * 64 + n * 16 + l15) * 32 + l4 * 8);
            #pragma unroll
            for (int m = 0; m < 4; m++)
                #pragma unroll
                for (int n = 0; n < 4; n++)
                    acc[m][n] = __builtin_amdgcn_mfma_f32_16x16x32_f16(af[m], bf[n], acc[m][n], 0, 0, 0);
            __syncthreads();
        }

        // score = ||e||^2 - 2 x.e = cn - acc/32  (acc = 64 * x.e)
        #pragma unroll
        for (int n = 0; n < 4; n++) {
            const int c = v0 + wc * 64 + n * 16 + l15;
            const float cn = cbn[c];
            #pragma unroll
            for (int m = 0; m < 4; m++)
                #pragma unroll
                for (int r = 0; r < 4; r++) {
                    float s = cn - acc[m][n][r] * 0.03125f;
                    if (s < rmin[m][r] || (s == rmin[m][r] && c < ridx[m][r])) {
                        rmin[m][r] = s; ridx[m][r] = c;
                    }
                }
        }
    }

    // reduce across the 16 lanes sharing each output row (l15 groups)
    #pragma unroll
    for (int m = 0; m < 4; m++)
        #pragma unroll
        for (int r = 0; r < 4; r++) {
            float mv = rmin[m][r];
            int   id = ridx[m][r];
            #pragma unroll
            for (int o = 1; o < 16; o <<= 1) {
                float om = __shfl_xor(mv, o, 64);
                int  oid = __shfl_xor(id, o, 64);
                if (om < mv || (om == mv && oid < id)) { mv = om; id = oid; }
            }
            if (l15 == 0) {
                const int grow = r0 + wr * 64 + m * 16 + l4 * 4 + r;
                pmin[grow * 32 + vgrp * 2 + wc] = mv;
                pidx[grow * 32 + vgrp * 2 + wc] = id;
            }
        }
}

// ---------- combine partials + gather + partial loss ----------
// block 256 = 4 waves, one row per wave; grid 16384/4
__global__ void combine_k(const float* __restrict__ lat, const float* __restrict__ cb,
                          const float* __restrict__ pmin, const int* __restrict__ pidx,
                          float* __restrict__ out_q, float* __restrict__ out_idx,
                          float* __restrict__ loss_part) {
    const int tid = threadIdx.x, lane = tid & 63, wv = tid >> 6;
    const int row = blockIdx.x * 4 + wv;

    float m = 3.4e38f; int id = 0x7fffffff;
    if (lane < 32) { m = pmin[row * 32 + lane]; id = pidx[row * 32 + lane]; }
    #pragma unroll
    for (int o = 32; o; o >>= 1) {
        float om = __shfl_xor(m, o, 64);
        int  oid = __shfl_xor(id, o, 64);
        if (om < m || (om == m && oid < id)) { m = om; id = oid; }
    }

    float4 q = *(const float4*)&cb[(size_t)id * DDIM + lane * 4];
    float4 x = *(const float4*)&lat[(size_t)row * DDIM + lane * 4];
    *(float4*)&out_q[(size_t)row * DDIM + lane * 4] = q;
    if (lane == 0) out_idx[row] = (float)id;

    float dx = q.x - x.x, dy = q.y - x.y, dz = q.z - x.z, dw = q.w - x.w;
    float s = dx * dx + dy * dy + dz * dz + dw * dw;
    #pragma unroll
    for (int o = 32; o; o >>= 1) s += __shfl_xor(s, o, 64);

    __shared__ float red[4];
    if (lane == 0) red[wv] = s;
    __syncthreads();
    if (tid == 0) loss_part[blockIdx.x] = red[0] + red[1] + red[2] + red[3];
}

// ---------- deterministic loss reduction ----------
__global__ void loss_k(const float* __restrict__ part, float* __restrict__ out_loss) {
    float s = 0.0f;
    for (int i = threadIdx.x; i < N_ROWS / 4; i += 256) s += part[i];
    #pragma unroll
    for (int m = 32; m; m >>= 1) s += __shfl_xor(s, m, 64);
    __shared__ float wsum[4];
    int lane = threadIdx.x & 63, w = threadIdx.x >> 6;
    if (lane == 0) wsum[w] = s;
    __syncthreads();
    if (threadIdx.x == 0) {
        float t = wsum[0] + wsum[1] + wsum[2] + wsum[3];
        *out_loss = (1.0f + BETA) * t / (float)((size_t)N_ROWS * DDIM);
    }
}

extern "C" void kernel_launch(void* const* d_in, const int* in_sizes, int n_in,
                              void* d_out, int out_size, void* d_ws, size_t ws_size,
                              hipStream_t stream) {
    const float* lat = (const float*)d_in[0];   // [16,32,32,256] fp32
    const float* cb  = (const float*)d_in[1];   // [8192,256] fp32

    float* ws = (float*)d_ws;
    f16*   Ah       = (f16*)ws;                          // 16384*512 f16 = 4194304 f-slots
    f16*   Bh       = (f16*)(ws + 4194304);              // 8192*512 f16 = 2097152 f-slots
    float* cbn      = ws + 4194304 + 2097152;            // 8192
    float* pmin     = cbn + VCODES;                      // 16384*32
    int*   pidx     = (int*)(pmin + N_ROWS * 32);        // 16384*32
    float* losspart = (float*)(pidx + N_ROWS * 32);      // 4096

    float* out_q    = (float*)d_out;                     // 4194304
    float* out_loss = out_q + (size_t)N_ROWS * DDIM;     // 1
    float* out_idx  = out_loss + 1;                      // 16384 (as fp32)

    split_lat<<<N_ROWS * DDIM / 1024, 256, 0, stream>>>(lat, Ah);
    split_cb<<<VCODES * DDIM / 1024, 256, 0, stream>>>(cb, Bh);
    cbnorm_k<<<VCODES / 4, 256, 0, stream>>>(cb, cbn);

    dim3 grid(N_ROWS / 128, VCODES / 512);
    vq_mfma<<<grid, 256, 0, stream>>>(Ah, Bh, cbn, pmin, pidx);

    combine_k<<<N_ROWS / 4, 256, 0, stream>>>(lat, cb, pmin, pidx,
                                              out_q, out_idx, losspart);
    loss_k<<<1, 256, 0, stream>>>(losspart, out_loss);
}